// Round 5
// baseline (921.056 us; speedup 1.0000x reference)
//
#include <hip/hip_runtime.h>

// Problem constants (N=8192 rows, D=256 features)
#define NN 8192
#define DD 256
#define ND_ (NN * DD)

#define NEG_SLOPE 0.1f

typedef _Float16 half8 __attribute__((ext_vector_type(8)));
typedef _Float16 half4 __attribute__((ext_vector_type(4)));
typedef float f32x4 __attribute__((ext_vector_type(4)));
typedef float f32x16 __attribute__((ext_vector_type(16)));

// ---------------------------------------------------------------------------
// prep_split: build transposed f16 hi/lo splits of u = h+d and v = h-d:
//   uT_hi/uT_lo/vT_hi/vT_lo : [DD=256 feature][NN=8192 node] f16
// Tile 64 node x 64 feature via LDS transpose. Grid 128*4 = 512 blocks.
// ---------------------------------------------------------------------------
__global__ __launch_bounds__(256, 2)
void prep_split_kernel(const float* __restrict__ h, const float* __restrict__ d,
                       _Float16* __restrict__ uT_hi, _Float16* __restrict__ uT_lo,
                       _Float16* __restrict__ vT_hi, _Float16* __restrict__ vT_lo) {
    __shared__ float s_h[64 * 68];
    __shared__ float s_d[64 * 68];
    const int b  = blockIdx.x;
    const int kt = b >> 2;          // node-tile 0..127
    const int ct = b & 3;           // feature-tile 0..3
    const int k0 = kt * 64;
    const int c0 = ct * 64;
    const int t  = threadIdx.x;

#pragma unroll
    for (int e = 0; e < 4; ++e) {
        int idx = e * 256 + t;
        int r   = idx >> 4;                  // node 0..63
        int c4  = (idx & 15) << 2;           // feature 0..60
        float4 hv = *(const float4*)&h[(size_t)(k0 + r) * DD + c0 + c4];
        float4 dv = *(const float4*)&d[(size_t)(k0 + r) * DD + c0 + c4];
        *(float4*)&s_h[r * 68 + c4] = hv;
        *(float4*)&s_d[r * 68 + c4] = dv;
    }
    __syncthreads();

#pragma unroll
    for (int e = 0; e < 2; ++e) {
        int idx = e * 256 + t;
        int c   = idx >> 3;                  // feature-in-tile 0..63
        int seg = idx & 7;                   // node chunk of 8
        half8 uh, ul, vh, vl;
#pragma unroll
        for (int m = 0; m < 8; ++m) {
            float hh = s_h[(seg * 8 + m) * 68 + c];
            float dd = s_d[(seg * 8 + m) * 68 + c];
            float uu = hh + dd;
            float vv = hh - dd;
            _Float16 a = (_Float16)uu;
            uh[m] = a;
            ul[m] = (_Float16)(uu - (float)a);
            _Float16 bb = (_Float16)vv;
            vh[m] = bb;
            vl[m] = (_Float16)(vv - (float)bb);
        }
        size_t go = (size_t)(c0 + c) * NN + k0 + seg * 8;
        *(half8*)&uT_hi[go] = uh;
        *(half8*)&uT_lo[go] = ul;
        *(half8*)&vT_hi[go] = vh;
        *(half8*)&vT_lo[go] = vl;
    }
}

// ---------------------------------------------------------------------------
// agg_mfma: fp32-emulated-via-f16x3 MFMA (32x32x16) of split-K partials:
//   P = (A + A^T) @ u      Q = (A^T - A) @ v
// stored as f16 in Pbuf/Qbuf [2 halves][NN][DD].
//
// Block: 64 rows x 256 cols, 512 threads (8 waves).
//   waves 0-3: P (cols cw*64..);  waves 4-7: Q.
//   Per wave: 64x64 tile = 2x2 frags of 32x32; f16x3 -> 24 MFMA / K-step(32).
// Grid: 256 blocks = 128 row-blocks x 2 K-halves.
// Global loads for iter i+1 are issued before iter i's MFMA (T14 async split).
// ---------------------------------------------------------------------------
__global__ __launch_bounds__(512, 2)
void agg_mfma_kernel(const float* __restrict__ alpha,
                     const _Float16* __restrict__ uT_hi, const _Float16* __restrict__ uT_lo,
                     const _Float16* __restrict__ vT_hi, const _Float16* __restrict__ vT_lo,
                     _Float16* __restrict__ Pbuf,   // [2][NN][DD]
                     _Float16* __restrict__ Qbuf) { // [2][NN][DD]
    // LDS carve (bytes):
    //  s_a1  : float [64][36]   raw A row-slab (transpose staging)   9216
    //  sS_hi/sS_lo/sD_hi/sD_lo : f16 [64 r][40 k-pitch]              4*5120
    //  sB[4] : f16 [256 c][40 k-pitch] (uT_hi,uT_lo,vT_hi,vT_lo)     4*20480
    __shared__ unsigned char smem[111616];
    float*    s_a1  = (float*)smem;
    _Float16* sS_hi = (_Float16*)(smem + 9216);
    _Float16* sS_lo = (_Float16*)(smem + 14336);
    _Float16* sD_hi = (_Float16*)(smem + 19456);
    _Float16* sD_lo = (_Float16*)(smem + 24576);
    _Float16* sB0   = (_Float16*)(smem + 29696);
    _Float16* sB1   = (_Float16*)(smem + 50176);
    _Float16* sB2   = (_Float16*)(smem + 70656);
    _Float16* sB3   = (_Float16*)(smem + 91136);

    const int b    = blockIdx.x;
    const int half = b & 1;
    const int rb   = b >> 1;
    const int I0   = rb * 64;
    const int t    = threadIdx.x;
    const int w    = t >> 6;
    const int lane = t & 63;

    const bool isP = (w < 4);
    const int  cw  = w & 3;                // 64-col band within 256

    const _Float16* aHi = isP ? sS_hi : sD_hi;
    const _Float16* aLo = isP ? sS_lo : sD_lo;
    const _Float16* bHi = isP ? sB0 : sB2;
    const _Float16* bLo = isP ? sB1 : sB3;

    const _Float16* gB[4] = {uT_hi, uT_lo, vT_hi, vT_lo};
    _Float16* sBp[4] = {sB0, sB1, sB2, sB3};

    f32x16 acc[2][2];
#pragma unroll
    for (int i = 0; i < 2; ++i)
#pragma unroll
        for (int j = 0; j < 2; ++j)
#pragma unroll
            for (int r = 0; r < 16; ++r) acc[i][j][r] = 0.f;

    // staging index precompute
    const int r_a1  = t >> 3;              // 0..63
    const int k4a   = (t & 7) << 2;        // 0..28
    const int kk    = t >> 4;              // 0..31   (col-slab / build k)
    const int rbase = t & 15;              // build row base (consecutive!)
    const int c0s   = t >> 2;              // 0..127  B-stage col base
    const int seg0  = t & 3;               // B-stage k-seg
    const int lrow  = lane & 31;
    const int lk    = (lane >> 5) << 3;    // 0 or 8

    const int kbase = half * (NN / 2);

    // prefetch registers
    float4 pA1;
    float  a2r[4];
    float4 pB[4][2];

    // ---- prologue: issue loads for iter 0 ----
    {
        const int k0g = kbase;
        pA1 = *(const float4*)&alpha[(size_t)(I0 + r_a1) * NN + k0g + k4a];
#pragma unroll
        for (int j = 0; j < 4; ++j)
            a2r[j] = alpha[(size_t)(k0g + kk) * NN + I0 + rbase + 16 * j];
#pragma unroll
        for (int arr = 0; arr < 4; ++arr)
#pragma unroll
            for (int rep = 0; rep < 2; ++rep) {
                int c = c0s + rep * 128;
                pB[arr][rep] = *(const float4*)&gB[arr][(size_t)c * NN + k0g + seg0 * 8];
            }
    }

    for (int it = 0; it < 128; ++it) {
        __syncthreads();   // previous iteration's LDS reads complete

        // ---- write staged data to LDS ----
        *(float4*)&s_a1[r_a1 * 36 + k4a] = pA1;
#pragma unroll
        for (int arr = 0; arr < 4; ++arr)
#pragma unroll
            for (int rep = 0; rep < 2; ++rep) {
                int c = c0s + rep * 128;
                *(float4*)&sBp[arr][c * 40 + seg0 * 8] = pB[arr][rep];
            }
        __syncthreads();   // s_a1 / sB ready

        // ---- build S = A^T+A, D = A^T-A tiles (f16 hi/lo, layout [r][k]) ----
#pragma unroll
        for (int j = 0; j < 4; ++j) {
            int row = rbase + 16 * j;               // 16 consecutive rows/group
            float tr = s_a1[row * 36 + kk];
            float sv = a2r[j] + tr;
            float dvv = a2r[j] - tr;
            int adr = row * 40 + kk;
            _Float16 sh = (_Float16)sv;
            sS_hi[adr] = sh;
            sS_lo[adr] = (_Float16)(sv - (float)sh);
            _Float16 dh = (_Float16)dvv;
            sD_hi[adr] = dh;
            sD_lo[adr] = (_Float16)(dvv - (float)dh);
        }

        // ---- issue next iteration's global loads (hide under MFMA) ----
        if (it != 127) {
            const int k0g = kbase + (it + 1) * 32;
            pA1 = *(const float4*)&alpha[(size_t)(I0 + r_a1) * NN + k0g + k4a];
#pragma unroll
            for (int j = 0; j < 4; ++j)
                a2r[j] = alpha[(size_t)(k0g + kk) * NN + I0 + rbase + 16 * j];
#pragma unroll
            for (int arr = 0; arr < 4; ++arr)
#pragma unroll
                for (int rep = 0; rep < 2; ++rep) {
                    int c = c0s + rep * 128;
                    pB[arr][rep] = *(const float4*)&gB[arr][(size_t)c * NN + k0g + seg0 * 8];
                }
        }
        __syncthreads();   // S/D ready

        // ---- inner: 24 MFMA (32x32x16) per wave ----
#pragma unroll
        for (int s = 0; s < 2; ++s) {
            half8 aH0 = *(const half8*)&aHi[(lrow) * 40 + s * 16 + lk];
            half8 aH1 = *(const half8*)&aHi[(32 + lrow) * 40 + s * 16 + lk];
            half8 aL0 = *(const half8*)&aLo[(lrow) * 40 + s * 16 + lk];
            half8 aL1 = *(const half8*)&aLo[(32 + lrow) * 40 + s * 16 + lk];
#pragma unroll
            for (int cf = 0; cf < 2; ++cf) {
                int cc = (cw * 64 + cf * 32 + lrow) * 40 + s * 16 + lk;
                half8 bH = *(const half8*)&bHi[cc];
                half8 bL = *(const half8*)&bLo[cc];
                acc[0][cf] = __builtin_amdgcn_mfma_f32_32x32x16_f16(aH0, bH, acc[0][cf], 0, 0, 0);
                acc[0][cf] = __builtin_amdgcn_mfma_f32_32x32x16_f16(aH0, bL, acc[0][cf], 0, 0, 0);
                acc[0][cf] = __builtin_amdgcn_mfma_f32_32x32x16_f16(aL0, bH, acc[0][cf], 0, 0, 0);
                acc[1][cf] = __builtin_amdgcn_mfma_f32_32x32x16_f16(aH1, bH, acc[1][cf], 0, 0, 0);
                acc[1][cf] = __builtin_amdgcn_mfma_f32_32x32x16_f16(aH1, bL, acc[1][cf], 0, 0, 0);
                acc[1][cf] = __builtin_amdgcn_mfma_f32_32x32x16_f16(aL1, bH, acc[1][cf], 0, 0, 0);
            }
        }
    }

    // ---- epilogue: write f16 partials ----
    // C/D layout (32x32): col = lane&31, row = (reg&3) + 8*(reg>>2) + 4*(lane>>5)
    _Float16* dst = (isP ? Pbuf : Qbuf) + (size_t)half * ND_;
#pragma unroll
    for (int rf = 0; rf < 2; ++rf)
#pragma unroll
        for (int cf = 0; cf < 2; ++cf)
#pragma unroll
            for (int reg = 0; reg < 16; ++reg) {
                int row = I0 + rf * 32 + (reg & 3) + ((reg >> 2) << 3) + ((lane >> 5) << 2);
                int col = cw * 64 + cf * 32 + (lane & 31);
                dst[(size_t)row * DD + col] = (_Float16)acc[rf][cf][reg];
            }
}

// ---------------------------------------------------------------------------
// stageB: combine P/Q partials into agg, then
//   out = leaky_relu( agg @ W1 + Y @ W2 )
// Block tile 64 x 128, 256 threads, 4x8 accum/thread, K=256 in BK=32 chunks.
// Grid 512: sel = b>>8 (0 = head output, 1 = dependent output).
// ---------------------------------------------------------------------------
__global__ __launch_bounds__(256, 2)
void stageB_kernel(const _Float16* __restrict__ Pbuf, const _Float16* __restrict__ Qbuf,
                   const float* __restrict__ head, const float* __restrict__ dep,
                   const float* __restrict__ alpha,
                   const float* __restrict__ Wah, const float* __restrict__ Wad,
                   const float* __restrict__ Wch, const float* __restrict__ Wcd,
                   float* __restrict__ out) {
    __shared__ float smem2[12544];
    __shared__ float s_dg[64];
    float* s_x  = smem2;            // [32][68] transposed X tile
    float* s_y  = smem2 + 2176;     // [32][68]
    float* s_w1 = smem2 + 4352;     // [32][128]
    float* s_w2 = smem2 + 8448;     // [32][128] -> 12544

    int b   = blockIdx.x;
    int sel = b >> 8;
    int rem = b & 255;
    int rb  = rem >> 1;
    int cb  = rem & 1;
    int I0  = rb * 64;
    int C0  = cb * 128;

    const float* Y  = sel ? dep : head;
    const float* W1 = sel ? Wad : Wah;
    const float* W2 = sel ? Wcd : Wch;
    float* dst = out + sel * ND_;

    int t  = threadIdx.x;
    int rg = t & 15, cg = t >> 4;
    int r0 = rg * 4, c0 = cg * 8;

    if (t < 64) s_dg[t] = alpha[(size_t)(I0 + t) * NN + I0 + t];

    float acc[4][8];
#pragma unroll
    for (int i = 0; i < 4; ++i)
#pragma unroll
        for (int j = 0; j < 8; ++j) acc[i][j] = 0.0f;

    for (int it = 0; it < 8; ++it) {
        int k0 = it * 32;
        __syncthreads();
#pragma unroll
        for (int e = 0; e < 2; ++e) {
            int idx = e * 256 + t;
            int r   = idx >> 3;              // 0..63
            int k4  = (idx & 7) << 2;        // 0..28
            size_t go = (size_t)(I0 + r) * DD + k0 + k4;
            half4 p0 = *(const half4*)&Pbuf[go];
            half4 p1 = *(const half4*)&Pbuf[ND_ + go];
            half4 q0 = *(const half4*)&Qbuf[go];
            half4 q1 = *(const half4*)&Qbuf[ND_ + go];
            float4 hv = *(const float4*)&head[go];
            float4 dv = *(const float4*)&dep[go];
            float dgv = s_dg[r];
            float hj[4] = {hv.x, hv.y, hv.z, hv.w};
            float dj[4] = {dv.x, dv.y, dv.z, dv.w};
#pragma unroll
            for (int j = 0; j < 4; ++j) {
                float Pv = (float)p0[j] + (float)p1[j];
                float Qv = (float)q0[j] + (float)q1[j];
                float uu = hj[j] + dj[j];
                float x  = (sel ? 0.5f * (Pv - Qv) : 0.5f * (Pv + Qv)) - dgv * uu;
                s_x[(k4 + j) * 68 + r] = x;
                s_y[(k4 + j) * 68 + r] = sel ? dj[j] : hj[j];
            }
        }
#pragma unroll
        for (int e = 0; e < 4; ++e) {
            int idx = e * 256 + t;
            int kkk = idx >> 5;
            int c4  = (idx & 31) << 2;
            *(float4*)&s_w1[kkk * 128 + c4] =
                *(const float4*)&W1[(size_t)(k0 + kkk) * DD + C0 + c4];
            *(float4*)&s_w2[kkk * 128 + c4] =
                *(const float4*)&W2[(size_t)(k0 + kkk) * DD + C0 + c4];
        }
        __syncthreads();
#pragma unroll 8
        for (int k = 0; k < 32; ++k) {
            float4 xv = *(const float4*)&s_x[k * 68 + r0];
            float4 yv = *(const float4*)&s_y[k * 68 + r0];
            float4 wa = *(const float4*)&s_w1[k * 128 + c0];
            float4 wb = *(const float4*)&s_w1[k * 128 + c0 + 4];
            float4 wc = *(const float4*)&s_w2[k * 128 + c0];
            float4 wd = *(const float4*)&s_w2[k * 128 + c0 + 4];
            float xs[4]  = {xv.x, xv.y, xv.z, xv.w};
            float ys[4]  = {yv.x, yv.y, yv.z, yv.w};
            float w1s[8] = {wa.x, wa.y, wa.z, wa.w, wb.x, wb.y, wb.z, wb.w};
            float w2s[8] = {wc.x, wc.y, wc.z, wc.w, wd.x, wd.y, wd.z, wd.w};
#pragma unroll
            for (int i = 0; i < 4; ++i)
#pragma unroll
                for (int j = 0; j < 8; ++j)
                    acc[i][j] += xs[i] * w1s[j] + ys[i] * w2s[j];
        }
    }

    // leaky relu + store
#pragma unroll
    for (int i = 0; i < 4; ++i) {
#pragma unroll
        for (int jv = 0; jv < 2; ++jv) {
            float4 o;
            float v0 = acc[i][4 * jv + 0];
            float v1 = acc[i][4 * jv + 1];
            float v2 = acc[i][4 * jv + 2];
            float v3 = acc[i][4 * jv + 3];
            o.x = v0 >= 0.0f ? v0 : NEG_SLOPE * v0;
            o.y = v1 >= 0.0f ? v1 : NEG_SLOPE * v1;
            o.z = v2 >= 0.0f ? v2 : NEG_SLOPE * v2;
            o.w = v3 >= 0.0f ? v3 : NEG_SLOPE * v3;
            *(float4*)&dst[(size_t)(I0 + r0 + i) * DD + C0 + c0 + 4 * jv] = o;
        }
    }
}

// ---------------------------------------------------------------------------
// kernel_launch
// workspace layout (_Float16 units):
//   uT_hi[ND] uT_lo[ND] vT_hi[ND] vT_lo[ND] P[2*ND] Q[2*ND] = 32 MB
// ---------------------------------------------------------------------------
extern "C" void kernel_launch(void* const* d_in, const int* in_sizes, int n_in,
                              void* d_out, int out_size, void* d_ws, size_t ws_size,
                              hipStream_t stream) {
    const float* head  = (const float*)d_in[0];
    const float* dep   = (const float*)d_in[1];
    const float* alpha = (const float*)d_in[2];
    const float* Wah   = (const float*)d_in[3];
    const float* Wad   = (const float*)d_in[4];
    const float* Wch   = (const float*)d_in[5];
    const float* Wcd   = (const float*)d_in[6];
    float* out = (float*)d_out;

    _Float16* ws    = (_Float16*)d_ws;
    _Float16* uT_hi = ws;
    _Float16* uT_lo = ws + (size_t)ND_;
    _Float16* vT_hi = ws + (size_t)2 * ND_;
    _Float16* vT_lo = ws + (size_t)3 * ND_;
    _Float16* Pbuf  = ws + (size_t)4 * ND_;   // [2][NN][DD]
    _Float16* Qbuf  = ws + (size_t)6 * ND_;   // [2][NN][DD]

    prep_split_kernel<<<512, 256, 0, stream>>>(head, dep, uT_hi, uT_lo, vT_hi, vT_lo);
    agg_mfma_kernel<<<256, 512, 0, stream>>>(alpha, uT_hi, uT_lo, vT_hi, vT_lo, Pbuf, Qbuf);
    stageB_kernel<<<512, 256, 0, stream>>>(Pbuf, Qbuf, head, dep, alpha,
                                           Wah, Wad, Wch, Wcd, out);
}

// Round 7
// 387.516 us; speedup vs baseline: 2.3768x; 2.3768x over previous
//
#include <hip/hip_runtime.h>

// Problem constants (N=8192 rows, D=256 features)
#define NN 8192
#define DD 256
#define ND_ (NN * DD)

#define NEG_SLOPE 0.1f

typedef _Float16 half8 __attribute__((ext_vector_type(8)));
typedef _Float16 half4 __attribute__((ext_vector_type(4)));
typedef float f32x4 __attribute__((ext_vector_type(4)));
typedef float f32x16 __attribute__((ext_vector_type(16)));

// async global->LDS, 16B per lane; lds dst = wave-uniform base + lane*16
__device__ __forceinline__ void ld_g2l16(const void* g, void* l) {
    __builtin_amdgcn_global_load_lds(
        (const __attribute__((address_space(1))) void*)g,
        (__attribute__((address_space(3))) void*)l, 16, 0, 0);
}

__device__ __forceinline__ unsigned pkhalf2(_Float16 a, _Float16 b) {
    unsigned short ua = __builtin_bit_cast(unsigned short, a);
    unsigned short ub = __builtin_bit_cast(unsigned short, b);
    return (unsigned)ua | ((unsigned)ub << 16);
}

// ---------------------------------------------------------------------------
// prep_split: build f16 hi/lo splits of u = h+d, v = h-d in the SWIZZLED,
// k-block-tiled layout agg consumes via linear global_load_lds:
//   element (c, k):  kb = k>>5, gd = (k>>3)&3, slot = gd ^ ((c>>1)&3)
//   offset = kb*8192 + c*32 + slot*8 + (k&7)      (f16 units)
// Grid 128 node-tiles x 4 feature-tiles = 512 blocks, 256 threads.
// ---------------------------------------------------------------------------
__global__ __launch_bounds__(256, 2)
void prep_split_kernel(const float* __restrict__ h, const float* __restrict__ d,
                       _Float16* __restrict__ uS_hi, _Float16* __restrict__ uS_lo,
                       _Float16* __restrict__ vS_hi, _Float16* __restrict__ vS_lo) {
    __shared__ float s_h[64 * 68];
    __shared__ float s_d[64 * 68];
    const int b  = blockIdx.x;
    const int kt = b >> 2;          // node-tile 0..127 (64 nodes)
    const int ct = b & 3;           // feature-tile 0..3 (64 features)
    const int k0 = kt * 64;
    const int c0 = ct * 64;
    const int t  = threadIdx.x;

#pragma unroll
    for (int e = 0; e < 4; ++e) {
        int idx = e * 256 + t;
        int r   = idx >> 4;                  // node 0..63
        int c4  = (idx & 15) << 2;           // feature 0..60
        float4 hv = *(const float4*)&h[(size_t)(k0 + r) * DD + c0 + c4];
        float4 dv = *(const float4*)&d[(size_t)(k0 + r) * DD + c0 + c4];
        *(float4*)&s_h[r * 68 + c4] = hv;
        *(float4*)&s_d[r * 68 + c4] = dv;
    }
    __syncthreads();

#pragma unroll
    for (int e = 0; e < 2; ++e) {
        int idx = e * 256 + t;
        int c   = idx >> 3;                  // feature-in-tile 0..63
        int seg = idx & 7;                   // node chunk of 8 (k' = seg*8)
        half8 uh, ul, vh, vl;
#pragma unroll
        for (int m = 0; m < 8; ++m) {
            float hh = s_h[(seg * 8 + m) * 68 + c];
            float dd = s_d[(seg * 8 + m) * 68 + c];
            float uu = hh + dd;
            float vv = hh - dd;
            _Float16 a = (_Float16)uu;
            uh[m] = a;
            ul[m] = (_Float16)(uu - (float)a);
            _Float16 bb = (_Float16)vv;
            vh[m] = bb;
            vl[m] = (_Float16)(vv - (float)bb);
        }
        int    cg   = c0 + c;
        int    kb   = kt * 2 + (seg >> 2);
        int    slot = (seg & 3) ^ ((cg >> 1) & 3);
        size_t go   = (size_t)kb * 8192 + (size_t)cg * 32 + slot * 8;
        *(half8*)&uS_hi[go] = uh;
        *(half8*)&uS_lo[go] = ul;
        *(half8*)&vS_hi[go] = vh;
        *(half8*)&vS_lo[go] = vl;
    }
}

// ---------------------------------------------------------------------------
// agg_mfma: fp32-emulated-via-f16x3 MFMA (32x32x16) of split-K partials:
//   P = (A + A^T) @ u      Q = (A^T - A) @ v
// stored as f16 in Pbuf/Qbuf [2 halves][NN][DD].
//
// Block: 64 rows x 256 cols, 512 threads (8 waves): waves 0-3 P, 4-7 Q.
// B tiles staged by global_load_lds from the pre-swizzled arrays (linear).
// Grid: 256 blocks = 128 row-blocks x 2 K-halves.
// ---------------------------------------------------------------------------
__global__ __launch_bounds__(512, 2)
void agg_mfma_kernel(const float* __restrict__ alpha,
                     const _Float16* __restrict__ uS_hi, const _Float16* __restrict__ uS_lo,
                     const _Float16* __restrict__ vS_hi, const _Float16* __restrict__ vS_lo,
                     _Float16* __restrict__ Pbuf,   // [2][NN][DD]
                     _Float16* __restrict__ Qbuf) { // [2][NN][DD]
    // LDS carve (bytes):
    //  s_a1 : f32 [64][36]                               9216
    //  sS_hi/sS_lo/sD_hi/sD_lo : f16 [64 r][40 kpitch]   4*5120 = 20480
    //  sB0..sB3 : f16 [256 c][32 k] linear (swizzled)    4*16384 = 65536
    __shared__ __align__(16) unsigned char smem[95232];
    float*    s_a1  = (float*)smem;
    _Float16* sS_hi = (_Float16*)(smem + 9216);
    _Float16* sS_lo = (_Float16*)(smem + 14336);
    _Float16* sD_hi = (_Float16*)(smem + 19456);
    _Float16* sD_lo = (_Float16*)(smem + 24576);
    _Float16* sB0   = (_Float16*)(smem + 29696);
    _Float16* sB1   = (_Float16*)(smem + 46080);
    _Float16* sB2   = (_Float16*)(smem + 62464);
    _Float16* sB3   = (_Float16*)(smem + 78848);

    const int b    = blockIdx.x;
    const int khalf = b & 1;
    const int rb   = b >> 1;
    const int I0   = rb * 64;
    const int t    = threadIdx.x;
    const int w    = t >> 6;
    const int lane = t & 63;

    const bool isP = (w < 4);
    const int  cw  = w & 3;                // 64-col band within 256

    const _Float16* aHi = isP ? sS_hi : sD_hi;
    const _Float16* aLo = isP ? sS_lo : sD_lo;
    const _Float16* bHi = isP ? sB0 : sB2;
    const _Float16* bLo = isP ? sB1 : sB3;

    const _Float16* gA[4] = {uS_hi, uS_lo, vS_hi, vS_lo};
    _Float16* sBp[4] = {sB0, sB1, sB2, sB3};

    f32x16 acc[2][2];
#pragma unroll
    for (int i = 0; i < 2; ++i)
#pragma unroll
        for (int j = 0; j < 2; ++j)
#pragma unroll
            for (int r = 0; r < 16; ++r) acc[i][j][r] = 0.f;

    // staging / build / mfma index precompute
    const int r_a1  = t >> 3;              // 0..63
    const int k4a   = (t & 7) << 2;        // 0..28
    const int rbase = t & 15;              // build row base
    const int kp    = (t >> 4) & 15;       // build k-pair (kk = 2kp, 2kp+1)
    const int dup   = t >> 8;              // 0: rows +0/+16, 1: rows +32/+48
    const int lrow  = lane & 31;
    const int lk    = (lane >> 5) << 3;    // 0 or 8

    const int kbase = khalf * (NN / 2);

    for (int it = 0; it < 128; ++it) {
        const int k0g = kbase + it * 32;
        const int kb  = khalf * 128 + it;
        __syncthreads();   // previous iteration's LDS reads complete

        // ---- B tiles: async global->LDS, fully linear per wave ----
        {
            size_t gbase = (size_t)kb * 8192 + (size_t)(w * 512 + lane * 8);
#pragma unroll
            for (int arr = 0; arr < 4; ++arr)
#pragma unroll
                for (int repp = 0; repp < 2; ++repp)
                    ld_g2l16(gA[arr] + gbase + repp * 4096,
                             (unsigned char*)sBp[arr] + repp * 8192 + w * 1024);
        }

        // ---- alpha slabs -> regs ----
        float4 pA1 = *(const float4*)&alpha[(size_t)(I0 + r_a1) * NN + k0g + k4a];
        float a2r[2][2];
#pragma unroll
        for (int jj = 0; jj < 2; ++jj)
#pragma unroll
            for (int e = 0; e < 2; ++e)
                a2r[jj][e] = alpha[(size_t)(k0g + 2 * kp + e) * NN +
                                   I0 + rbase + 16 * (dup * 2 + jj)];
        *(float4*)&s_a1[r_a1 * 36 + k4a] = pA1;
        __syncthreads();   // s_a1 + B tiles visible

        // ---- build S = A^T+A, D = A^T-A  (f16 hi/lo, [row][k] pitch 40) ----
#pragma unroll
        for (int jj = 0; jj < 2; ++jj) {
            int row = rbase + 16 * (dup * 2 + jj);
            float2 tr = *(const float2*)&s_a1[row * 36 + 2 * kp];
            float s0 = a2r[jj][0] + tr.x, s1 = a2r[jj][1] + tr.y;
            float d0 = a2r[jj][0] - tr.x, d1 = a2r[jj][1] - tr.y;
            int adr = row * 20 + kp;       // u32 index (pitch 40 f16 = 20 u32)
            _Float16 sh0 = (_Float16)s0, sh1 = (_Float16)s1;
            ((unsigned*)sS_hi)[adr] = pkhalf2(sh0, sh1);
            ((unsigned*)sS_lo)[adr] =
                pkhalf2((_Float16)(s0 - (float)sh0), (_Float16)(s1 - (float)sh1));
            _Float16 dh0 = (_Float16)d0, dh1 = (_Float16)d1;
            ((unsigned*)sD_hi)[adr] = pkhalf2(dh0, dh1);
            ((unsigned*)sD_lo)[adr] =
                pkhalf2((_Float16)(d0 - (float)dh0), (_Float16)(d1 - (float)dh1));
        }
        __syncthreads();   // S/D ready

        // ---- inner: 24 MFMA (32x32x16) per wave ----
#pragma unroll
        for (int s = 0; s < 2; ++s) {
            half8 aH0 = *(const half8*)&aHi[(lrow) * 40 + s * 16 + lk];
            half8 aH1 = *(const half8*)&aHi[(32 + lrow) * 40 + s * 16 + lk];
            half8 aL0 = *(const half8*)&aLo[(lrow) * 40 + s * 16 + lk];
            half8 aL1 = *(const half8*)&aLo[(32 + lrow) * 40 + s * 16 + lk];
            int gd = s * 2 + (lane >> 5);
#pragma unroll
            for (int cf = 0; cf < 2; ++cf) {
                int c  = cw * 64 + cf * 32 + lrow;
                int sl = gd ^ ((c >> 1) & 3);
                int bi = c * 32 + sl * 8;
                half8 bH = *(const half8*)&bHi[bi];
                half8 bL = *(const half8*)&bLo[bi];
                acc[0][cf] = __builtin_amdgcn_mfma_f32_32x32x16_f16(aH0, bH, acc[0][cf], 0, 0, 0);
                acc[0][cf] = __builtin_amdgcn_mfma_f32_32x32x16_f16(aH0, bL, acc[0][cf], 0, 0, 0);
                acc[0][cf] = __builtin_amdgcn_mfma_f32_32x32x16_f16(aL0, bH, acc[0][cf], 0, 0, 0);
                acc[1][cf] = __builtin_amdgcn_mfma_f32_32x32x16_f16(aH1, bH, acc[1][cf], 0, 0, 0);
                acc[1][cf] = __builtin_amdgcn_mfma_f32_32x32x16_f16(aH1, bL, acc[1][cf], 0, 0, 0);
                acc[1][cf] = __builtin_amdgcn_mfma_f32_32x32x16_f16(aL1, bH, acc[1][cf], 0, 0, 0);
            }
        }
    }

    // ---- epilogue: write f16 partials ----
    // C/D layout (32x32): col = lane&31, row = (reg&3) + 8*(reg>>2) + 4*(lane>>5)
    _Float16* dst = (isP ? Pbuf : Qbuf) + (size_t)khalf * ND_;
#pragma unroll
    for (int rf = 0; rf < 2; ++rf)
#pragma unroll
        for (int cf = 0; cf < 2; ++cf)
#pragma unroll
            for (int reg = 0; reg < 16; ++reg) {
                int row = I0 + rf * 32 + (reg & 3) + ((reg >> 2) << 3) + ((lane >> 5) << 2);
                int col = cw * 64 + cf * 32 + (lane & 31);
                dst[(size_t)row * DD + col] = (_Float16)acc[rf][cf][reg];
            }
}

// ---------------------------------------------------------------------------
// stageB: combine P/Q partials into agg, then
//   out = leaky_relu( agg @ W1 + Y @ W2 )
// Block tile 64 x 128, 256 threads, 4x8 accum/thread, K=256 in BK=32 chunks.
// Grid 512: sel = b>>8 (0 = head output, 1 = dependent output).
// ---------------------------------------------------------------------------
__global__ __launch_bounds__(256, 2)
void stageB_kernel(const _Float16* __restrict__ Pbuf, const _Float16* __restrict__ Qbuf,
                   const float* __restrict__ head, const float* __restrict__ dep,
                   const float* __restrict__ alpha,
                   const float* __restrict__ Wah, const float* __restrict__ Wad,
                   const float* __restrict__ Wch, const float* __restrict__ Wcd,
                   float* __restrict__ out) {
    __shared__ float smem2[12544];
    __shared__ float s_dg[64];
    float* s_x  = smem2;            // [32][68] transposed X tile
    float* s_y  = smem2 + 2176;     // [32][68]
    float* s_w1 = smem2 + 4352;     // [32][128]
    float* s_w2 = smem2 + 8448;     // [32][128] -> 12544

    int b   = blockIdx.x;
    int sel = b >> 8;
    int rem = b & 255;
    int rb  = rem >> 1;
    int cb  = rem & 1;
    int I0  = rb * 64;
    int C0  = cb * 128;

    const float* Y  = sel ? dep : head;
    const float* W1 = sel ? Wad : Wah;
    const float* W2 = sel ? Wcd : Wch;
    float* dst = out + sel * ND_;

    int t  = threadIdx.x;
    int rg = t & 15, cg = t >> 4;
    int r0 = rg * 4, c0 = cg * 8;

    if (t < 64) s_dg[t] = alpha[(size_t)(I0 + t) * NN + I0 + t];

    float acc[4][8];
#pragma unroll
    for (int i = 0; i < 4; ++i)
#pragma unroll
        for (int j = 0; j < 8; ++j) acc[i][j] = 0.0f;

    for (int it = 0; it < 8; ++it) {
        int k0 = it * 32;
        __syncthreads();
#pragma unroll
        for (int e = 0; e < 2; ++e) {
            int idx = e * 256 + t;
            int r   = idx >> 3;              // 0..63
            int k4  = (idx & 7) << 2;        // 0..28
            size_t go = (size_t)(I0 + r) * DD + k0 + k4;
            half4 p0 = *(const half4*)&Pbuf[go];
            half4 p1 = *(const half4*)&Pbuf[ND_ + go];
            half4 q0 = *(const half4*)&Qbuf[go];
            half4 q1 = *(const half4*)&Qbuf[ND_ + go];
            float4 hv = *(const float4*)&head[go];
            float4 dv = *(const float4*)&dep[go];
            float dgv = s_dg[r];
            float hj[4] = {hv.x, hv.y, hv.z, hv.w};
            float dj[4] = {dv.x, dv.y, dv.z, dv.w};
#pragma unroll
            for (int j = 0; j < 4; ++j) {
                float Pv = (float)p0[j] + (float)p1[j];
                float Qv = (float)q0[j] + (float)q1[j];
                float uu = hj[j] + dj[j];
                float x  = (sel ? 0.5f * (Pv - Qv) : 0.5f * (Pv + Qv)) - dgv * uu;
                s_x[(k4 + j) * 68 + r] = x;
                s_y[(k4 + j) * 68 + r] = sel ? dj[j] : hj[j];
            }
        }
#pragma unroll
        for (int e = 0; e < 4; ++e) {
            int idx = e * 256 + t;
            int kkk = idx >> 5;
            int c4  = (idx & 31) << 2;
            *(float4*)&s_w1[kkk * 128 + c4] =
                *(const float4*)&W1[(size_t)(k0 + kkk) * DD + C0 + c4];
            *(float4*)&s_w2[kkk * 128 + c4] =
                *(const float4*)&W2[(size_t)(k0 + kkk) * DD + C0 + c4];
        }
        __syncthreads();
#pragma unroll 8
        for (int k = 0; k < 32; ++k) {
            float4 xv = *(const float4*)&s_x[k * 68 + r0];
            float4 yv = *(const float4*)&s_y[k * 68 + r0];
            float4 wa = *(const float4*)&s_w1[k * 128 + c0];
            float4 wb = *(const float4*)&s_w1[k * 128 + c0 + 4];
            float4 wc = *(const float4*)&s_w2[k * 128 + c0];
            float4 wd = *(const float4*)&s_w2[k * 128 + c0 + 4];
            float xs[4]  = {xv.x, xv.y, xv.z, xv.w};
            float ys[4]  = {yv.x, yv.y, yv.z, yv.w};
            float w1s[8] = {wa.x, wa.y, wa.z, wa.w, wb.x, wb.y, wb.z, wb.w};
            float w2s[8] = {wc.x, wc.y, wc.z, wc.w, wd.x, wd.y, wd.z, wd.w};
#pragma unroll
            for (int i = 0; i < 4; ++i)
#pragma unroll
                for (int j = 0; j < 8; ++j)
                    acc[i][j] += xs[i] * w1s[j] + ys[i] * w2s[j];
        }
    }

    // leaky relu + store
#pragma unroll
    for (int i = 0; i < 4; ++i) {
#pragma unroll
        for (int jv = 0; jv < 2; ++jv) {
            float4 o;
            float v0 = acc[i][4 * jv + 0];
            float v1 = acc[i][4 * jv + 1];
            float v2 = acc[i][4 * jv + 2];
            float v3 = acc[i][4 * jv + 3];
            o.x = v0 >= 0.0f ? v0 : NEG_SLOPE * v0;
            o.y = v1 >= 0.0f ? v1 : NEG_SLOPE * v1;
            o.z = v2 >= 0.0f ? v2 : NEG_SLOPE * v2;
            o.w = v3 >= 0.0f ? v3 : NEG_SLOPE * v3;
            *(float4*)&dst[(size_t)(I0 + r0 + i) * DD + C0 + c0 + 4 * jv] = o;
        }
    }
}

// ---------------------------------------------------------------------------
// kernel_launch
// workspace (_Float16 units): uS_hi[ND] uS_lo[ND] vS_hi[ND] vS_lo[ND]
//                             P[2*ND] Q[2*ND]  = 8*ND f16 = 32 MB
// ---------------------------------------------------------------------------
extern "C" void kernel_launch(void* const* d_in, const int* in_sizes, int n_in,
                              void* d_out, int out_size, void* d_ws, size_t ws_size,
                              hipStream_t stream) {
    const float* head  = (const float*)d_in[0];
    const float* dep   = (const float*)d_in[1];
    const float* alpha = (const float*)d_in[2];
    const float* Wah   = (const float*)d_in[3];
    const float* Wad   = (const float*)d_in[4];
    const float* Wch   = (const float*)d_in[5];
    const float* Wcd   = (const float*)d_in[6];
    float* out = (float*)d_out;

    _Float16* ws    = (_Float16*)d_ws;
    _Float16* uS_hi = ws;
    _Float16* uS_lo = ws + (size_t)ND_;
    _Float16* vS_hi = ws + (size_t)2 * ND_;
    _Float16* vS_lo = ws + (size_t)3 * ND_;
    _Float16* Pbuf  = ws + (size_t)4 * ND_;   // [2][NN][DD]
    _Float16* Qbuf  = ws + (size_t)6 * ND_;   // [2][NN][DD]

    prep_split_kernel<<<512, 256, 0, stream>>>(head, dep, uS_hi, uS_lo, vS_hi, vS_lo);
    agg_mfma_kernel<<<256, 512, 0, stream>>>(alpha, uS_hi, uS_lo, vS_hi, vS_lo, Pbuf, Qbuf);
    stageB_kernel<<<512, 256, 0, stream>>>(Pbuf, Qbuf, head, dep, alpha,
                                           Wah, Wad, Wch, Wcd, out);
}

// Round 8
// 379.469 us; speedup vs baseline: 2.4272x; 1.0212x over previous
//
#include <hip/hip_runtime.h>

// Problem constants (N=8192 rows, D=256 features)
#define NN 8192
#define DD 256
#define ND_ (NN * DD)

#define NEG_SLOPE 0.1f

typedef _Float16 half8 __attribute__((ext_vector_type(8)));
typedef _Float16 half4 __attribute__((ext_vector_type(4)));
typedef float f32x4 __attribute__((ext_vector_type(4)));
typedef float f32x16 __attribute__((ext_vector_type(16)));

// async global->LDS, 16B per lane; lds dst = wave-uniform base + lane*16
__device__ __forceinline__ void ld_g2l16(const void* g, void* l) {
    __builtin_amdgcn_global_load_lds(
        (const __attribute__((address_space(1))) void*)g,
        (__attribute__((address_space(3))) void*)l, 16, 0, 0);
}

__device__ __forceinline__ unsigned pkhalf2(_Float16 a, _Float16 b) {
    unsigned short ua = __builtin_bit_cast(unsigned short, a);
    unsigned short ub = __builtin_bit_cast(unsigned short, b);
    return (unsigned)ua | ((unsigned)ub << 16);
}

// ---------------------------------------------------------------------------
// prep_split: build f16 hi/lo splits of u = h+d, v = h-d in the SWIZZLED,
// k-block-tiled layout agg consumes via linear global_load_lds:
//   element (c, k):  kb = k>>5, gd = (k>>3)&3, slot = gd ^ ((c>>1)&3)
//   offset = kb*8192 + c*32 + slot*8 + (k&7)      (f16 units)
// Grid 128 node-tiles x 4 feature-tiles = 512 blocks, 256 threads.
// ---------------------------------------------------------------------------
__global__ __launch_bounds__(256, 2)
void prep_split_kernel(const float* __restrict__ h, const float* __restrict__ d,
                       _Float16* __restrict__ uS_hi, _Float16* __restrict__ uS_lo,
                       _Float16* __restrict__ vS_hi, _Float16* __restrict__ vS_lo) {
    __shared__ float s_h[64 * 68];
    __shared__ float s_d[64 * 68];
    const int b  = blockIdx.x;
    const int kt = b >> 2;          // node-tile 0..127 (64 nodes)
    const int ct = b & 3;           // feature-tile 0..3 (64 features)
    const int k0 = kt * 64;
    const int c0 = ct * 64;
    const int t  = threadIdx.x;

#pragma unroll
    for (int e = 0; e < 4; ++e) {
        int idx = e * 256 + t;
        int r   = idx >> 4;                  // node 0..63
        int c4  = (idx & 15) << 2;           // feature 0..60
        float4 hv = *(const float4*)&h[(size_t)(k0 + r) * DD + c0 + c4];
        float4 dv = *(const float4*)&d[(size_t)(k0 + r) * DD + c0 + c4];
        *(float4*)&s_h[r * 68 + c4] = hv;
        *(float4*)&s_d[r * 68 + c4] = dv;
    }
    __syncthreads();

#pragma unroll
    for (int e = 0; e < 2; ++e) {
        int idx = e * 256 + t;
        int c   = idx >> 3;                  // feature-in-tile 0..63
        int seg = idx & 7;                   // node chunk of 8 (k' = seg*8)
        half8 uh, ul, vh, vl;
#pragma unroll
        for (int m = 0; m < 8; ++m) {
            float hh = s_h[(seg * 8 + m) * 68 + c];
            float dd = s_d[(seg * 8 + m) * 68 + c];
            float uu = hh + dd;
            float vv = hh - dd;
            _Float16 a = (_Float16)uu;
            uh[m] = a;
            ul[m] = (_Float16)(uu - (float)a);
            _Float16 bb = (_Float16)vv;
            vh[m] = bb;
            vl[m] = (_Float16)(vv - (float)bb);
        }
        int    cg   = c0 + c;
        int    kb   = kt * 2 + (seg >> 2);
        int    slot = (seg & 3) ^ ((cg >> 1) & 3);
        size_t go   = (size_t)kb * 8192 + (size_t)cg * 32 + slot * 8;
        *(half8*)&uS_hi[go] = uh;
        *(half8*)&uS_lo[go] = ul;
        *(half8*)&vS_hi[go] = vh;
        *(half8*)&vS_lo[go] = vl;
    }
}

// ---------------------------------------------------------------------------
// agg_mfma: fp32-emulated-via-f16x3 MFMA (32x32x16) of split-K partials:
//   P = (A + A^T) @ u      Q = (A^T - A) @ v
// stored as f16 in Pbuf/Qbuf [2 halves][NN][DD].
//
// Block: 64 rows x 128 cols, 512 threads (8 waves): waves 0-3 P, 4-7 Q,
// each wave owns a 64x32 output band (acc[2] of 32x32 frags).
// LDS 62.5 KB -> 2 blocks/CU (16 waves/CU) so one block's MFMA overlaps the
// sibling block's staging/build (TLP pipelining, m114 mechanism).
// Grid: 512 = 128 rb x 2 cb x 2 khalf; blockIdx bits: [0]=khalf,
// [2:1]+[·>>4]=rb, [3]=cb so sibling cb-blocks are 8 apart (same XCD under
// round-robin dispatch -> shared alpha slabs in L2).
// ---------------------------------------------------------------------------
__global__ __launch_bounds__(512, 4)
void agg_mfma_kernel(const float* __restrict__ alpha,
                     const _Float16* __restrict__ uS_hi, const _Float16* __restrict__ uS_lo,
                     const _Float16* __restrict__ vS_hi, const _Float16* __restrict__ vS_lo,
                     _Float16* __restrict__ Pbuf,   // [2][NN][DD]
                     _Float16* __restrict__ Qbuf) { // [2][NN][DD]
    // LDS carve (bytes):
    //  s_a1 : f32 [64][36]                               9216
    //  sS_hi/sS_lo/sD_hi/sD_lo : f16 [64 r][40 kpitch]   4*5120 = 20480
    //  sB0..sB3 : f16 [128 c][32 k] linear (swizzled)    4*8192 = 32768
    __shared__ __align__(16) unsigned char smem[62464];
    float*    s_a1  = (float*)smem;
    _Float16* sS_hi = (_Float16*)(smem + 9216);
    _Float16* sS_lo = (_Float16*)(smem + 14336);
    _Float16* sD_hi = (_Float16*)(smem + 19456);
    _Float16* sD_lo = (_Float16*)(smem + 24576);
    _Float16* sB0   = (_Float16*)(smem + 29696);
    _Float16* sB1   = (_Float16*)(smem + 37888);
    _Float16* sB2   = (_Float16*)(smem + 46080);
    _Float16* sB3   = (_Float16*)(smem + 54272);

    const int raw   = blockIdx.x;
    const int khalf = raw & 1;
    const int cb    = (raw >> 3) & 1;
    const int rb    = ((raw >> 1) & 3) | ((raw >> 4) << 2);
    const int I0    = rb * 64;
    const int C0    = cb * 128;
    const int t     = threadIdx.x;
    const int w     = t >> 6;
    const int lane  = t & 63;

    const bool isP = (w < 4);
    const int  cw  = w & 3;                // 32-col band within the 128

    const _Float16* aHi = isP ? sS_hi : sD_hi;
    const _Float16* aLo = isP ? sS_lo : sD_lo;
    const _Float16* bHi = isP ? sB0 : sB2;
    const _Float16* bLo = isP ? sB1 : sB3;

    const _Float16* gA[4] = {uS_hi, uS_lo, vS_hi, vS_lo};
    _Float16* sBp[4] = {sB0, sB1, sB2, sB3};

    f32x16 acc[2];
#pragma unroll
    for (int i = 0; i < 2; ++i)
#pragma unroll
        for (int r = 0; r < 16; ++r) acc[i][r] = 0.f;

    // staging / build / mfma index precompute
    const int r_a1  = t >> 3;              // 0..63
    const int k4a   = (t & 7) << 2;        // 0..28
    const int rbase = t & 15;              // build row base
    const int kp    = (t >> 4) & 15;       // build k-pair (kk = 2kp, 2kp+1)
    const int dup   = t >> 8;              // 0: rows +0/+16, 1: rows +32/+48
    const int lrow  = lane & 31;
    const int lk    = (lane >> 5) << 3;    // 0 or 8

    const int kbase = khalf * (NN / 2);

    for (int it = 0; it < 128; ++it) {
        const int k0g = kbase + it * 32;
        const int kb  = khalf * 128 + it;
        __syncthreads();   // previous iteration's LDS reads complete

        // ---- B tiles: async global->LDS, fully linear per wave ----
        {
            size_t gbase = (size_t)kb * 8192 + cb * 4096 + (size_t)(w * 512 + lane * 8);
#pragma unroll
            for (int arr = 0; arr < 4; ++arr)
                ld_g2l16(gA[arr] + gbase, (unsigned char*)sBp[arr] + w * 1024);
        }

        // ---- alpha slabs -> regs ----
        float4 pA1 = *(const float4*)&alpha[(size_t)(I0 + r_a1) * NN + k0g + k4a];
        float a2r[2][2];
#pragma unroll
        for (int jj = 0; jj < 2; ++jj)
#pragma unroll
            for (int e = 0; e < 2; ++e)
                a2r[jj][e] = alpha[(size_t)(k0g + 2 * kp + e) * NN +
                                   I0 + rbase + 16 * (dup * 2 + jj)];
        *(float4*)&s_a1[r_a1 * 36 + k4a] = pA1;
        __syncthreads();   // s_a1 + B tiles visible

        // ---- build S = A^T+A, D = A^T-A  (f16 hi/lo, [row][k] pitch 40) ----
#pragma unroll
        for (int jj = 0; jj < 2; ++jj) {
            int row = rbase + 16 * (dup * 2 + jj);
            float2 tr = *(const float2*)&s_a1[row * 36 + 2 * kp];
            float s0 = a2r[jj][0] + tr.x, s1 = a2r[jj][1] + tr.y;
            float d0 = a2r[jj][0] - tr.x, d1 = a2r[jj][1] - tr.y;
            int adr = row * 20 + kp;       // u32 index (pitch 40 f16 = 20 u32)
            _Float16 sh0 = (_Float16)s0, sh1 = (_Float16)s1;
            ((unsigned*)sS_hi)[adr] = pkhalf2(sh0, sh1);
            ((unsigned*)sS_lo)[adr] =
                pkhalf2((_Float16)(s0 - (float)sh0), (_Float16)(s1 - (float)sh1));
            _Float16 dh0 = (_Float16)d0, dh1 = (_Float16)d1;
            ((unsigned*)sD_hi)[adr] = pkhalf2(dh0, dh1);
            ((unsigned*)sD_lo)[adr] =
                pkhalf2((_Float16)(d0 - (float)dh0), (_Float16)(d1 - (float)dh1));
        }
        __syncthreads();   // S/D ready

        // ---- inner: 12 MFMA (32x32x16) per wave ----
        const int c_local = cw * 32 + lrow;
        __builtin_amdgcn_s_setprio(1);
#pragma unroll
        for (int s = 0; s < 2; ++s) {
            half8 aH0 = *(const half8*)&aHi[(lrow) * 40 + s * 16 + lk];
            half8 aH1 = *(const half8*)&aHi[(32 + lrow) * 40 + s * 16 + lk];
            half8 aL0 = *(const half8*)&aLo[(lrow) * 40 + s * 16 + lk];
            half8 aL1 = *(const half8*)&aLo[(32 + lrow) * 40 + s * 16 + lk];
            int gd = s * 2 + (lane >> 5);
            int sl = gd ^ ((c_local >> 1) & 3);
            int bi = c_local * 32 + sl * 8;
            half8 bH = *(const half8*)&bHi[bi];
            half8 bL = *(const half8*)&bLo[bi];
            acc[0] = __builtin_amdgcn_mfma_f32_32x32x16_f16(aH0, bH, acc[0], 0, 0, 0);
            acc[0] = __builtin_amdgcn_mfma_f32_32x32x16_f16(aH0, bL, acc[0], 0, 0, 0);
            acc[0] = __builtin_amdgcn_mfma_f32_32x32x16_f16(aL0, bH, acc[0], 0, 0, 0);
            acc[1] = __builtin_amdgcn_mfma_f32_32x32x16_f16(aH1, bH, acc[1], 0, 0, 0);
            acc[1] = __builtin_amdgcn_mfma_f32_32x32x16_f16(aH1, bL, acc[1], 0, 0, 0);
            acc[1] = __builtin_amdgcn_mfma_f32_32x32x16_f16(aL1, bH, acc[1], 0, 0, 0);
        }
        __builtin_amdgcn_s_setprio(0);
    }

    // ---- epilogue: write f16 partials ----
    // C/D layout (32x32): col = lane&31, row = (reg&3) + 8*(reg>>2) + 4*(lane>>5)
    _Float16* dst = (isP ? Pbuf : Qbuf) + (size_t)khalf * ND_;
    const int colw = C0 + cw * 32 + (lane & 31);
#pragma unroll
    for (int rf = 0; rf < 2; ++rf)
#pragma unroll
        for (int reg = 0; reg < 16; ++reg) {
            int row = I0 + rf * 32 + (reg & 3) + ((reg >> 2) << 3) + ((lane >> 5) << 2);
            dst[(size_t)row * DD + colw] = (_Float16)acc[rf][reg];
        }
}

// ---------------------------------------------------------------------------
// stageB: combine P/Q partials into agg, then
//   out = leaky_relu( agg @ W1 + Y @ W2 )
// Block tile 64 x 128, 256 threads, 4x8 accum/thread, K=256 in BK=32 chunks.
// Grid 512: sel = b>>8 (0 = head output, 1 = dependent output).
// ---------------------------------------------------------------------------
__global__ __launch_bounds__(256, 2)
void stageB_kernel(const _Float16* __restrict__ Pbuf, const _Float16* __restrict__ Qbuf,
                   const float* __restrict__ head, const float* __restrict__ dep,
                   const float* __restrict__ alpha,
                   const float* __restrict__ Wah, const float* __restrict__ Wad,
                   const float* __restrict__ Wch, const float* __restrict__ Wcd,
                   float* __restrict__ out) {
    __shared__ float smem2[12544];
    __shared__ float s_dg[64];
    float* s_x  = smem2;            // [32][68] transposed X tile
    float* s_y  = smem2 + 2176;     // [32][68]
    float* s_w1 = smem2 + 4352;     // [32][128]
    float* s_w2 = smem2 + 8448;     // [32][128] -> 12544

    int b   = blockIdx.x;
    int sel = b >> 8;
    int rem = b & 255;
    int rb  = rem >> 1;
    int cb  = rem & 1;
    int I0  = rb * 64;
    int C0  = cb * 128;

    const float* Y  = sel ? dep : head;
    const float* W1 = sel ? Wad : Wah;
    const float* W2 = sel ? Wcd : Wch;
    float* dst = out + sel * ND_;

    int t  = threadIdx.x;
    int rg = t & 15, cg = t >> 4;
    int r0 = rg * 4, c0 = cg * 8;

    if (t < 64) s_dg[t] = alpha[(size_t)(I0 + t) * NN + I0 + t];

    float acc[4][8];
#pragma unroll
    for (int i = 0; i < 4; ++i)
#pragma unroll
        for (int j = 0; j < 8; ++j) acc[i][j] = 0.0f;

    for (int it = 0; it < 8; ++it) {
        int k0 = it * 32;
        __syncthreads();
#pragma unroll
        for (int e = 0; e < 2; ++e) {
            int idx = e * 256 + t;
            int r   = idx >> 3;              // 0..63
            int k4  = (idx & 7) << 2;        // 0..28
            size_t go = (size_t)(I0 + r) * DD + k0 + k4;
            half4 p0 = *(const half4*)&Pbuf[go];
            half4 p1 = *(const half4*)&Pbuf[ND_ + go];
            half4 q0 = *(const half4*)&Qbuf[go];
            half4 q1 = *(const half4*)&Qbuf[ND_ + go];
            float4 hv = *(const float4*)&head[go];
            float4 dv = *(const float4*)&dep[go];
            float dgv = s_dg[r];
            float hj[4] = {hv.x, hv.y, hv.z, hv.w};
            float dj[4] = {dv.x, dv.y, dv.z, dv.w};
#pragma unroll
            for (int j = 0; j < 4; ++j) {
                float Pv = (float)p0[j] + (float)p1[j];
                float Qv = (float)q0[j] + (float)q1[j];
                float uu = hj[j] + dj[j];
                float x  = (sel ? 0.5f * (Pv - Qv) : 0.5f * (Pv + Qv)) - dgv * uu;
                s_x[(k4 + j) * 68 + r] = x;
                s_y[(k4 + j) * 68 + r] = sel ? dj[j] : hj[j];
            }
        }
#pragma unroll
        for (int e = 0; e < 4; ++e) {
            int idx = e * 256 + t;
            int kkk = idx >> 5;
            int c4  = (idx & 31) << 2;
            *(float4*)&s_w1[kkk * 128 + c4] =
                *(const float4*)&W1[(size_t)(k0 + kkk) * DD + C0 + c4];
            *(float4*)&s_w2[kkk * 128 + c4] =
                *(const float4*)&W2[(size_t)(k0 + kkk) * DD + C0 + c4];
        }
        __syncthreads();
#pragma unroll 8
        for (int k = 0; k < 32; ++k) {
            float4 xv = *(const float4*)&s_x[k * 68 + r0];
            float4 yv = *(const float4*)&s_y[k * 68 + r0];
            float4 wa = *(const float4*)&s_w1[k * 128 + c0];
            float4 wb = *(const float4*)&s_w1[k * 128 + c0 + 4];
            float4 wc = *(const float4*)&s_w2[k * 128 + c0];
            float4 wd = *(const float4*)&s_w2[k * 128 + c0 + 4];
            float xs[4]  = {xv.x, xv.y, xv.z, xv.w};
            float ys[4]  = {yv.x, yv.y, yv.z, yv.w};
            float w1s[8] = {wa.x, wa.y, wa.z, wa.w, wb.x, wb.y, wb.z, wb.w};
            float w2s[8] = {wc.x, wc.y, wc.z, wc.w, wd.x, wd.y, wd.z, wd.w};
#pragma unroll
            for (int i = 0; i < 4; ++i)
#pragma unroll
                for (int j = 0; j < 8; ++j)
                    acc[i][j] += xs[i] * w1s[j] + ys[i] * w2s[j];
        }
    }

    // leaky relu + store
#pragma unroll
    for (int i = 0; i < 4; ++i) {
#pragma unroll
        for (int jv = 0; jv < 2; ++jv) {
            float4 o;
            float v0 = acc[i][4 * jv + 0];
            float v1 = acc[i][4 * jv + 1];
            float v2 = acc[i][4 * jv + 2];
            float v3 = acc[i][4 * jv + 3];
            o.x = v0 >= 0.0f ? v0 : NEG_SLOPE * v0;
            o.y = v1 >= 0.0f ? v1 : NEG_SLOPE * v1;
            o.z = v2 >= 0.0f ? v2 : NEG_SLOPE * v2;
            o.w = v3 >= 0.0f ? v3 : NEG_SLOPE * v3;
            *(float4*)&dst[(size_t)(I0 + r0 + i) * DD + C0 + c0 + 4 * jv] = o;
        }
    }
}

// ---------------------------------------------------------------------------
// kernel_launch
// workspace (_Float16 units): uS_hi[ND] uS_lo[ND] vS_hi[ND] vS_lo[ND]
//                             P[2*ND] Q[2*ND]  = 8*ND f16 = 32 MB
// ---------------------------------------------------------------------------
extern "C" void kernel_launch(void* const* d_in, const int* in_sizes, int n_in,
                              void* d_out, int out_size, void* d_ws, size_t ws_size,
                              hipStream_t stream) {
    const float* head  = (const float*)d_in[0];
    const float* dep   = (const float*)d_in[1];
    const float* alpha = (const float*)d_in[2];
    const float* Wah   = (const float*)d_in[3];
    const float* Wad   = (const float*)d_in[4];
    const float* Wch   = (const float*)d_in[5];
    const float* Wcd   = (const float*)d_in[6];
    float* out = (float*)d_out;

    _Float16* ws    = (_Float16*)d_ws;
    _Float16* uS_hi = ws;
    _Float16* uS_lo = ws + (size_t)ND_;
    _Float16* vS_hi = ws + (size_t)2 * ND_;
    _Float16* vS_lo = ws + (size_t)3 * ND_;
    _Float16* Pbuf  = ws + (size_t)4 * ND_;   // [2][NN][DD]
    _Float16* Qbuf  = ws + (size_t)6 * ND_;   // [2][NN][DD]

    prep_split_kernel<<<512, 256, 0, stream>>>(head, dep, uS_hi, uS_lo, vS_hi, vS_lo);
    agg_mfma_kernel<<<512, 512, 0, stream>>>(alpha, uS_hi, uS_lo, vS_hi, vS_lo, Pbuf, Qbuf);
    stageB_kernel<<<512, 256, 0, stream>>>(Pbuf, Qbuf, head, dep, alpha,
                                           Wah, Wad, Wch, Wcd, out);
}